// Round 1
// baseline (9161.726 us; speedup 1.0000x reference)
//
#include <hip/hip_runtime.h>
#include <hip/hip_bf16.h>
#include <stdint.h>

#define S_LEN 512
#define BATCH 64
#define DDIM  512
#define HID   512
#define SB    32768   // S_LEN*BATCH
#define G4H   2048    // 4*HID

typedef __attribute__((ext_vector_type(8))) short bf16x8;
typedef __attribute__((ext_vector_type(4))) short short4v;
typedef __attribute__((ext_vector_type(4))) float f32x4;

__device__ __forceinline__ float bf2f(short s) {
  return __uint_as_float(((unsigned)(unsigned short)s) << 16);
}

__device__ __forceinline__ void gload_lds16(const void* g, void* l) {
  __builtin_amdgcn_global_load_lds(
      (const __attribute__((address_space(1))) void*)g,
      (__attribute__((address_space(3))) void*)l, 16, 0, 0);
}

// ---------- prep kernels ----------

__global__ void k_f32_to_bf16(const float* __restrict__ src,
                              __hip_bfloat16* __restrict__ dst, int n) {
  int i = (blockIdx.x * blockDim.x + threadIdx.x) * 8;
  if (i >= n) return;
  float4 a = *(const float4*)(src + i);
  float4 b = *(const float4*)(src + i + 4);
  __hip_bfloat16 t[8];
  t[0] = __float2bfloat16(a.x); t[1] = __float2bfloat16(a.y);
  t[2] = __float2bfloat16(a.z); t[3] = __float2bfloat16(a.w);
  t[4] = __float2bfloat16(b.x); t[5] = __float2bfloat16(b.y);
  t[6] = __float2bfloat16(b.z); t[7] = __float2bfloat16(b.w);
  *(bf16x8*)(dst + i) = *(bf16x8*)t;
}

// permute rows g*HID+j -> p=j*4+g, cast to bf16. src: [4H][K], dst: [2048][K]
__global__ void k_permW(const float* __restrict__ src,
                        __hip_bfloat16* __restrict__ dst, int K) {
  int idx = blockIdx.x * 256 + threadIdx.x;   // p*K + k
  int p = idx / K, k = idx - p * K;
  int g = p & 3, j = p >> 2;
  dst[idx] = __float2bfloat16(src[(size_t)(g * HID + j) * K + k]);
}

__global__ void k_permB(const float* __restrict__ bih, const float* __restrict__ bhh,
                        float* __restrict__ dst) {
  int p = blockIdx.x * 256 + threadIdx.x;  // 2048
  int g = p & 3, j = p >> 2;
  dst[p] = bih[g * HID + j] + bhh[g * HID + j];
}

// ---------- input-projection GEMM: G[d][m][p] = A[m][:] . W[d*2048+p][:] + bias ----------
// A: [32768][K] bf16 row-major. W: [4096][K] bf16 (permuted rows). G: [2][32768][2048] bf16.
__global__ __launch_bounds__(256) void k_gemm_in(
    const __hip_bfloat16* __restrict__ A,
    const __hip_bfloat16* __restrict__ W,
    const float* __restrict__ bsumL,     // [2][2048]
    __hip_bfloat16* __restrict__ G,
    int K) {
  __shared__ uint4 lds4[2048];           // 32KB: A tile 16KB, B tile 16KB
  char* ldsA = (char*)lds4;
  char* ldsB = (char*)lds4 + 16384;
  int tid = threadIdx.x, lane = tid & 63, wid = tid >> 6;
  int wm = wid >> 1, wn = wid & 1;
  int bm = blockIdx.x, by = blockIdx.y;
  int lr = lane & 15, lk = lane >> 4;
  f32x4 acc[4][4] = {};
  const char* gA = (const char*)A;
  const char* gW = (const char*)W;
  for (int kk = 0; kk < K; kk += 64) {
    #pragma unroll
    for (int i = 0; i < 4; i++) {
      int ch = i * 256 + tid;            // 0..1023, 16B chunks; 8 per row
      int row = ch >> 3, c16 = ch & 7;
      gload_lds16(gA + (size_t)(bm * 128 + row) * (K * 2) + kk * 2 + c16 * 16,
                  ldsA + (i * 256 + wid * 64) * 16);
      gload_lds16(gW + (size_t)(by * 128 + row) * (K * 2) + kk * 2 + c16 * 16,
                  ldsB + (i * 256 + wid * 64) * 16);
    }
    __syncthreads();
    #pragma unroll
    for (int ks = 0; ks < 2; ks++) {
      bf16x8 af[4], bfr[4];
      #pragma unroll
      for (int mi = 0; mi < 4; mi++) {
        int r = wm * 64 + mi * 16 + lr;
        af[mi] = *(const bf16x8*)(ldsA + r * 128 + ks * 64 + lk * 16);
      }
      #pragma unroll
      for (int ni = 0; ni < 4; ni++) {
        int r = wn * 64 + ni * 16 + lr;
        bfr[ni] = *(const bf16x8*)(ldsB + r * 128 + ks * 64 + lk * 16);
      }
      #pragma unroll
      for (int mi = 0; mi < 4; mi++)
        #pragma unroll
        for (int ni = 0; ni < 4; ni++)
          acc[mi][ni] = __builtin_amdgcn_mfma_f32_16x16x32_bf16(
              af[mi], bfr[ni], acc[mi][ni], 0, 0, 0);
    }
    __syncthreads();
  }
  // epilogue: add bias, store bf16
  #pragma unroll
  for (int ni = 0; ni < 4; ni++) {
    int n = by * 128 + wn * 64 + ni * 16 + lr;
    int d = n >> 11, p = n & 2047;
    float bias = bsumL[d * 2048 + p];
    #pragma unroll
    for (int mi = 0; mi < 4; mi++) {
      int mbase = bm * 128 + wm * 64 + mi * 16 + lk * 4;
      #pragma unroll
      for (int r = 0; r < 4; r++) {
        int m = mbase + r;
        G[((size_t)d * SB + m) * 2048 + p] =
            __float2bfloat16(acc[mi][ni][r] + bias);
      }
    }
  }
}

// ---------- per-timestep scan kernel ----------
// grid (32 n-tiles, 2 dirs), 256 threads. Each WG: 64 gate-cols (16 hidden units),
// all 64 batches. gates = G[t] + h_{prev} @ Whh_slice^T, then LSTM cell.
__global__ __launch_bounds__(256) void k_step(
    const __hip_bfloat16* __restrict__ G,    // [2][SB][2048]
    const __hip_bfloat16* __restrict__ Whp,  // [2][2048][512] (this layer)
    __hip_bfloat16* __restrict__ Y,          // [SB][1024] (this layer)
    float* __restrict__ C,                   // [2][64][512]
    const float* __restrict__ mask,          // [S][B]
    float* __restrict__ outH,                // d_out h-region (layer1) or null
    float* __restrict__ hn,                  // per-layer base
    float* __restrict__ cn,
    int step) {
  __shared__ uint4 smem4[4096];              // 64KB
  char* ldsH = (char*)smem4;                 // [64 rows][512B]  (256 k-elems, chunked)
  char* ldsW = (char*)smem4 + 32768;         // [64 rows][512B]
  float* gatesF = (float*)smem4;             // reuse: [64][68]
  int tid = threadIdx.x, lane = tid & 63, wid = tid >> 6;
  int bn = blockIdx.x;                       // 0..31
  int dir = blockIdx.y;                      // 0..1
  int t = dir ? (S_LEN - 1 - step) : step;
  int wm = wid >> 1, wn = wid & 1;
  int lr = lane & 15, lk = lane >> 4;
  f32x4 acc[2][2] = {};

  if (step > 0) {
    int tprev = dir ? t + 1 : t - 1;
    const char* srcH = (const char*)Y + (size_t)tprev * 64 * 2048 + dir * 1024;
    const char* srcW = (const char*)Whp + (size_t)(dir * 2048 + bn * 64) * 1024;
    #pragma unroll
    for (int kc = 0; kc < 2; kc++) {
      uint4 tH[8], tW[8];
      #pragma unroll
      for (int i = 0; i < 8; i++) {
        int ch = i * 256 + tid;              // 2048 chunks = 64 rows x 32
        int row = ch >> 5, c16 = ch & 31;
        tH[i] = *(const uint4*)(srcH + (size_t)row * 2048 + kc * 512 + c16 * 16);
        tW[i] = *(const uint4*)(srcW + (size_t)row * 1024 + kc * 512 + c16 * 16);
      }
      #pragma unroll
      for (int i = 0; i < 8; i++) {
        int ch = i * 256 + tid;
        int row = ch >> 5, c16 = ch & 31;
        int sw = (c16 * 16) ^ ((row & 7) << 4);
        *(uint4*)(ldsH + row * 512 + sw) = tH[i];
        *(uint4*)(ldsW + row * 512 + sw) = tW[i];
      }
      __syncthreads();
      #pragma unroll
      for (int ks = 0; ks < 8; ks++) {
        bf16x8 a[2], b[2];
        #pragma unroll
        for (int mi = 0; mi < 2; mi++) {
          int r = wm * 32 + mi * 16 + lr;
          a[mi] = *(const bf16x8*)(ldsH + r * 512 +
                                   (((ks * 64 + lk * 16)) ^ ((r & 7) << 4)));
        }
        #pragma unroll
        for (int ni = 0; ni < 2; ni++) {
          int r = wn * 32 + ni * 16 + lr;
          b[ni] = *(const bf16x8*)(ldsW + r * 512 +
                                   (((ks * 64 + lk * 16)) ^ ((r & 7) << 4)));
        }
        #pragma unroll
        for (int mi = 0; mi < 2; mi++)
          #pragma unroll
          for (int ni = 0; ni < 2; ni++)
            acc[mi][ni] = __builtin_amdgcn_mfma_f32_16x16x32_bf16(
                a[mi], b[ni], acc[mi][ni], 0, 0, 0);
      }
      __syncthreads();
    }
    // dump gates to LDS (f32, padded stride 68)
    #pragma unroll
    for (int mi = 0; mi < 2; mi++)
      #pragma unroll
      for (int ni = 0; ni < 2; ni++) {
        int b_ = wm * 32 + mi * 16 + lk * 4;
        int col = wn * 32 + ni * 16 + lr;
        #pragma unroll
        for (int r = 0; r < 4; r++)
          gatesF[(b_ + r) * 68 + col] = acc[mi][ni][r];
      }
    __syncthreads();
  }

  // cell update: 64 batches x 16 units
  #pragma unroll
  for (int it = 0; it < 4; it++) {
    int item = it * 256 + tid;
    int b = item >> 4, u = item & 15;
    int ug = bn * 16 + u;
    float gi = 0.f, gf = 0.f, gg = 0.f, go = 0.f;
    if (step > 0) {
      gi = gatesF[b * 68 + u * 4 + 0];
      gf = gatesF[b * 68 + u * 4 + 1];
      gg = gatesF[b * 68 + u * 4 + 2];
      go = gatesF[b * 68 + u * 4 + 3];
    }
    const __hip_bfloat16* gp =
        G + ((size_t)dir * SB + (size_t)t * 64 + b) * 2048 + bn * 64 + u * 4;
    short4v gv = *(const short4v*)gp;
    gi += bf2f(gv[0]); gf += bf2f(gv[1]); gg += bf2f(gv[2]); go += bf2f(gv[3]);
    float cprev = (step > 0) ? C[(dir * 64 + b) * 512 + ug] : 0.f;
    float m = mask[t * 64 + b];
    float si = 1.f / (1.f + __expf(-gi));
    float sf = 1.f / (1.f + __expf(-gf));
    float so = 1.f / (1.f + __expf(-go));
    float tg = 1.f - 2.f / (1.f + __expf(2.f * gg));
    float c2 = sf * cprev + si * tg;
    float h2 = so * (1.f - 2.f / (1.f + __expf(2.f * c2)));
    h2 *= m; c2 *= m;
    C[(dir * 64 + b) * 512 + ug] = c2;
    size_t oidx = ((size_t)t * 64 + b) * 1024 + dir * 512 + ug;
    Y[oidx] = __float2bfloat16(h2);
    if (outH) outH[oidx] = h2;
    if (step == S_LEN - 1) {
      size_t fi = (size_t)b * 1024 + dir * 512 + ug;
      hn[fi] = h2; cn[fi] = c2;
    }
  }
}

// ---------- launcher ----------

extern "C" void kernel_launch(void* const* d_in, const int* in_sizes, int n_in,
                              void* d_out, int out_size, void* d_ws, size_t ws_size,
                              hipStream_t stream) {
  const float* x    = (const float*)d_in[0];
  const float* mask = (const float*)d_in[1];
  // ld order: 0=l0f, 1=l0b, 2=l1f, 3=l1b
  const float* Wih[4] = {(const float*)d_in[2], (const float*)d_in[6],
                         (const float*)d_in[10], (const float*)d_in[14]};
  const float* Whh[4] = {(const float*)d_in[3], (const float*)d_in[7],
                         (const float*)d_in[11], (const float*)d_in[15]};
  const float* bih[4] = {(const float*)d_in[4], (const float*)d_in[8],
                         (const float*)d_in[12], (const float*)d_in[16]};
  const float* bhh[4] = {(const float*)d_in[5], (const float*)d_in[9],
                         (const float*)d_in[13], (const float*)d_in[17]};

  char* ws = (char*)d_ws;
  __hip_bfloat16* Xbf   = (__hip_bfloat16*)(ws);                 // 33,554,432
  __hip_bfloat16* Y0    = (__hip_bfloat16*)(ws + 33554432);      // 67,108,864
  __hip_bfloat16* Y1    = (__hip_bfloat16*)(ws + 100663296);     // 67,108,864
  __hip_bfloat16* WpIh0 = (__hip_bfloat16*)(ws + 167772160);     // [2][2048][512]   4 MB
  __hip_bfloat16* WpIh1 = (__hip_bfloat16*)(ws + 171966464);     // [2][2048][1024]  8 MB
  __hip_bfloat16* WpHh  = (__hip_bfloat16*)(ws + 180355072);     // [4][2048][512]   8 MB
  float*          bsum  = (float*)(ws + 188743680);              // [4][2048]
  float*          Cst   = (float*)(ws + 188776448);              // [2][64][512]
  __hip_bfloat16* Gbuf  = (__hip_bfloat16*)(ws + 189038592);     // [2][SB][2048] 268 MB
  // total ws needed: 457,474,048 bytes

  float* out = (float*)d_out;
  float* hn = out + (size_t)S_LEN * BATCH * 1024;   // + 33,554,432
  float* cn = hn + 2 * BATCH * 1024;                // + 131,072

  // prep
  k_f32_to_bf16<<<8192, 256, 0, stream>>>(x, Xbf, SB * DDIM);
  for (int ld = 0; ld < 4; ld++) {
    int K = (ld < 2) ? 512 : 1024;
    __hip_bfloat16* dst = (ld < 2) ? (WpIh0 + (size_t)ld * 2048 * 512)
                                   : (WpIh1 + (size_t)(ld - 2) * 2048 * 1024);
    k_permW<<<(2048 * K) / 256, 256, 0, stream>>>(Wih[ld], dst, K);
    k_permW<<<(2048 * 512) / 256, 256, 0, stream>>>(Whh[ld], WpHh + (size_t)ld * 2048 * 512, 512);
    k_permB<<<8, 256, 0, stream>>>(bih[ld], bhh[ld], bsum + ld * 2048);
  }

  // layer 0
  k_gemm_in<<<dim3(256, 32), 256, 0, stream>>>(Xbf, WpIh0, bsum, Gbuf, 512);
  for (int s = 0; s < S_LEN; s++)
    k_step<<<dim3(32, 2), 256, 0, stream>>>(Gbuf, WpHh, Y0, Cst, mask,
                                            nullptr, hn, cn, s);
  // layer 1
  k_gemm_in<<<dim3(256, 32), 256, 0, stream>>>(Y0, WpIh1, bsum + 2 * 2048, Gbuf, 1024);
  for (int s = 0; s < S_LEN; s++)
    k_step<<<dim3(32, 2), 256, 0, stream>>>(Gbuf, WpHh + 2 * 2048 * 512, Y1, Cst, mask,
                                            out, hn + 2 * BATCH * 512, cn + 2 * BATCH * 512, s);
}

// Round 2
// 7914.572 us; speedup vs baseline: 1.1576x; 1.1576x over previous
//
#include <hip/hip_runtime.h>
#include <hip/hip_bf16.h>
#include <stdint.h>

#define S_LEN 512
#define BATCH 64
#define DDIM  512
#define HID   512
#define SB    32768   // S_LEN*BATCH

typedef __attribute__((ext_vector_type(8))) short bf16x8;
typedef __attribute__((ext_vector_type(4))) short short4v;
typedef __attribute__((ext_vector_type(4))) float f32x4;

struct __align__(128) Bar { unsigned cnt; unsigned gen; };

__device__ __forceinline__ float bf2f(short s) {
  return __uint_as_float(((unsigned)(unsigned short)s) << 16);
}

__device__ __forceinline__ void gload_lds16(const void* g, void* l) {
  __builtin_amdgcn_global_load_lds(
      (const __attribute__((address_space(1))) void*)g,
      (__attribute__((address_space(3))) void*)l, 16, 0, 0);
}

// ---------- prep kernels ----------

__global__ void k_f32_to_bf16(const float* __restrict__ src,
                              __hip_bfloat16* __restrict__ dst, int n) {
  int i = (blockIdx.x * blockDim.x + threadIdx.x) * 8;
  if (i >= n) return;
  float4 a = *(const float4*)(src + i);
  float4 b = *(const float4*)(src + i + 4);
  __hip_bfloat16 t[8];
  t[0] = __float2bfloat16(a.x); t[1] = __float2bfloat16(a.y);
  t[2] = __float2bfloat16(a.z); t[3] = __float2bfloat16(a.w);
  t[4] = __float2bfloat16(b.x); t[5] = __float2bfloat16(b.y);
  t[6] = __float2bfloat16(b.z); t[7] = __float2bfloat16(b.w);
  *(bf16x8*)(dst + i) = *(bf16x8*)t;
}

// permute rows g*HID+j -> p=j*4+g, cast to bf16. src: [4H][K], dst: [2048][K]
__global__ void k_permW(const float* __restrict__ src,
                        __hip_bfloat16* __restrict__ dst, int K) {
  int idx = blockIdx.x * 256 + threadIdx.x;
  int p = idx / K, k = idx - p * K;
  int g = p & 3, j = p >> 2;
  dst[idx] = __float2bfloat16(src[(size_t)(g * HID + j) * K + k]);
}

__global__ void k_permB(const float* __restrict__ bih, const float* __restrict__ bhh,
                        float* __restrict__ dst) {
  int p = blockIdx.x * 256 + threadIdx.x;
  int g = p & 3, j = p >> 2;
  dst[p] = bih[g * HID + j] + bhh[g * HID + j];
}

// ---------- input-projection GEMM (m97 structure, proven in R1) ----------
__global__ __launch_bounds__(256) void k_gemm_in(
    const __hip_bfloat16* __restrict__ A,
    const __hip_bfloat16* __restrict__ W,
    const float* __restrict__ bsumL,
    __hip_bfloat16* __restrict__ G,
    int K) {
  __shared__ uint4 lds4[2048];
  char* ldsA = (char*)lds4;
  char* ldsB = (char*)lds4 + 16384;
  int tid = threadIdx.x, lane = tid & 63, wid = tid >> 6;
  int wm = wid >> 1, wn = wid & 1;
  int bm = blockIdx.x, by = blockIdx.y;
  int lr = lane & 15, lk = lane >> 4;
  f32x4 acc[4][4] = {};
  const char* gA = (const char*)A;
  const char* gW = (const char*)W;
  for (int kk = 0; kk < K; kk += 64) {
    #pragma unroll
    for (int i = 0; i < 4; i++) {
      int ch = i * 256 + tid;
      int row = ch >> 3, c16 = ch & 7;
      gload_lds16(gA + (size_t)(bm * 128 + row) * (K * 2) + kk * 2 + c16 * 16,
                  ldsA + (i * 256 + wid * 64) * 16);
      gload_lds16(gW + (size_t)(by * 128 + row) * (K * 2) + kk * 2 + c16 * 16,
                  ldsB + (i * 256 + wid * 64) * 16);
    }
    __syncthreads();
    #pragma unroll
    for (int ks = 0; ks < 2; ks++) {
      bf16x8 af[4], bfr[4];
      #pragma unroll
      for (int mi = 0; mi < 4; mi++) {
        int r = wm * 64 + mi * 16 + lr;
        af[mi] = *(const bf16x8*)(ldsA + r * 128 + ks * 64 + lk * 16);
      }
      #pragma unroll
      for (int ni = 0; ni < 4; ni++) {
        int r = wn * 64 + ni * 16 + lr;
        bfr[ni] = *(const bf16x8*)(ldsB + r * 128 + ks * 64 + lk * 16);
      }
      #pragma unroll
      for (int mi = 0; mi < 4; mi++)
        #pragma unroll
        for (int ni = 0; ni < 4; ni++)
          acc[mi][ni] = __builtin_amdgcn_mfma_f32_16x16x32_bf16(
              af[mi], bfr[ni], acc[mi][ni], 0, 0, 0);
    }
    __syncthreads();
  }
  #pragma unroll
  for (int ni = 0; ni < 4; ni++) {
    int n = by * 128 + wn * 64 + ni * 16 + lr;
    int d = n >> 11, p = n & 2047;
    float bias = bsumL[d * 2048 + p];
    #pragma unroll
    for (int mi = 0; mi < 4; mi++) {
      int mbase = bm * 128 + wm * 64 + mi * 16 + lk * 4;
      #pragma unroll
      for (int r = 0; r < 4; r++) {
        int m = mbase + r;
        G[((size_t)d * SB + m) * 2048 + p] =
            __float2bfloat16(acc[mi][ni][r] + bias);
      }
    }
  }
}

// ---------- persistent scan kernel: one launch per layer ----------
// grid 64 blocks (bn 0..31, dir 0..1) x 512 threads (8 waves).
// Wave (wm=wid>>1, wn=wid&1): rows wm*16 (one 16-batch m-tile), cols wn*32.
// Whh slice held in registers as MFMA B-fragments; c-state in registers.
__global__ __launch_bounds__(512, 1) void k_scan(
    const __hip_bfloat16* __restrict__ G,    // [2][SB][2048]
    const __hip_bfloat16* __restrict__ Whp,  // [2][2048][512] this layer
    __hip_bfloat16* __restrict__ Y,          // [SB][1024]
    const float* __restrict__ mask,          // [S][B]
    float* __restrict__ outH,                // f32 h out (layer1) or null
    float* __restrict__ hn, float* __restrict__ cn,
    Bar* __restrict__ bars) {                // [2] per-dir
  __shared__ char ldsH[65536];               // [64 rows][1024B], swizzled
  float* gatesF = (float*)ldsH;              // reuse: [64][68] f32
  int tid = threadIdx.x, lane = tid & 63, wid = tid >> 6;
  int bn = blockIdx.x & 31;
  int dir = blockIdx.x >> 5;
  int wm = wid >> 1, wn = wid & 1;
  int lr = lane & 15, lk = lane >> 4;
  int arow = wm * 16 + lr;
  Bar* bar = bars + dir;
  const __hip_bfloat16* Gd = G + (size_t)dir * SB * 2048;

  // load Whh B-fragments: wave wn covers cols wn*32..+31, full K=512
  bf16x8 bfrag[16][2];
  {
    const __hip_bfloat16* w0 =
        Whp + (size_t)(dir * 2048 + bn * 64 + wn * 32 + lr) * 512;
    #pragma unroll
    for (int ni = 0; ni < 2; ni++)
      #pragma unroll
      for (int ks = 0; ks < 16; ks++)
        bfrag[ks][ni] = *(const bf16x8*)(w0 + (size_t)ni * 16 * 512 + ks * 32 + lk * 8);
  }

  float creg[2] = {0.f, 0.f};

  for (int s = 0; s < S_LEN; ++s) {
    int t = dir ? (S_LEN - 1 - s) : s;
    // issue G loads early (HBM latency hidden under staging+MFMA)
    short4v gv[2];
    #pragma unroll
    for (int it = 0; it < 2; ++it) {
      int item = it * 512 + tid;
      int b = item >> 4, u = item & 15;
      gv[it] = *(const short4v*)(Gd + ((size_t)t * 64 + b) * 2048 + bn * 64 + u * 4);
    }
    f32x4 acc[2] = {};
    if (s > 0) {
      int tprev = dir ? t + 1 : t - 1;
      const char* srcH = (const char*)Y + (size_t)tprev * 131072 + dir * 1024;
      uint4 tH[8];
      #pragma unroll
      for (int i = 0; i < 8; ++i) {
        int ch = i * 512 + tid, row = ch >> 6, c16 = ch & 63;
        tH[i] = *(const uint4*)(srcH + (size_t)row * 2048 + c16 * 16);
      }
      #pragma unroll
      for (int i = 0; i < 8; ++i) {
        int ch = i * 512 + tid, row = ch >> 6, c16 = ch & 63;
        *(uint4*)(ldsH + row * 1024 + ((c16 * 16) ^ ((row & 7) << 4))) = tH[i];
      }
      __syncthreads();
      #pragma unroll
      for (int ks = 0; ks < 16; ++ks) {
        bf16x8 a = *(const bf16x8*)(
            ldsH + arow * 1024 + ((ks * 64 + lk * 16) ^ ((lr & 7) << 4)));
        acc[0] = __builtin_amdgcn_mfma_f32_16x16x32_bf16(a, bfrag[ks][0], acc[0], 0, 0, 0);
        acc[1] = __builtin_amdgcn_mfma_f32_16x16x32_bf16(a, bfrag[ks][1], acc[1], 0, 0, 0);
      }
      __syncthreads();
      #pragma unroll
      for (int ni = 0; ni < 2; ++ni)
        #pragma unroll
        for (int r = 0; r < 4; ++r)
          gatesF[(wm * 16 + lk * 4 + r) * 68 + wn * 32 + ni * 16 + lr] = acc[ni][r];
      __syncthreads();
    }
    // cell update: 2 items per thread
    #pragma unroll
    for (int it = 0; it < 2; ++it) {
      int item = it * 512 + tid;
      int b = item >> 4, u = item & 15;
      int ug = bn * 16 + u;
      float gi = 0.f, gf = 0.f, gg = 0.f, go = 0.f;
      if (s > 0) {
        gi = gatesF[b * 68 + u * 4 + 0];
        gf = gatesF[b * 68 + u * 4 + 1];
        gg = gatesF[b * 68 + u * 4 + 2];
        go = gatesF[b * 68 + u * 4 + 3];
      }
      gi += bf2f(gv[it][0]); gf += bf2f(gv[it][1]);
      gg += bf2f(gv[it][2]); go += bf2f(gv[it][3]);
      float m = mask[t * 64 + b];
      float si = 1.f / (1.f + __expf(-gi));
      float sf = 1.f / (1.f + __expf(-gf));
      float so = 1.f / (1.f + __expf(-go));
      float tg = 1.f - 2.f / (1.f + __expf(2.f * gg));
      float c2 = sf * creg[it] + si * tg;
      float h2 = so * (1.f - 2.f / (1.f + __expf(2.f * c2)));
      h2 *= m; c2 *= m;
      creg[it] = c2;
      size_t oidx = ((size_t)t * 64 + b) * 1024 + dir * 512 + ug;
      Y[oidx] = __float2bfloat16(h2);
      if (outH) outH[oidx] = h2;
      if (s == S_LEN - 1) {
        size_t fi = (size_t)b * 1024 + dir * 512 + ug;
        hn[fi] = h2; cn[fi] = c2;
      }
    }
    // per-direction grid barrier (32 blocks), agent scope
    if (s < S_LEN - 1) {
      __syncthreads();
      if (tid == 0) {
        unsigned prev = __hip_atomic_fetch_add(&bar->cnt, 1, __ATOMIC_ACQ_REL,
                                               __HIP_MEMORY_SCOPE_AGENT);
        if (prev == 31) {
          __hip_atomic_store(&bar->cnt, 0, __ATOMIC_RELAXED,
                             __HIP_MEMORY_SCOPE_AGENT);
          __hip_atomic_fetch_add(&bar->gen, 1, __ATOMIC_RELEASE,
                                 __HIP_MEMORY_SCOPE_AGENT);
        } else {
          int guard = 0;
          while (__hip_atomic_load(&bar->gen, __ATOMIC_ACQUIRE,
                                   __HIP_MEMORY_SCOPE_AGENT) <= (unsigned)s) {
            __builtin_amdgcn_s_sleep(1);
            if (++guard > (1 << 24)) break;  // hang-proof bail
          }
        }
      }
      __syncthreads();
    }
  }
}

// ---------- launcher ----------

extern "C" void kernel_launch(void* const* d_in, const int* in_sizes, int n_in,
                              void* d_out, int out_size, void* d_ws, size_t ws_size,
                              hipStream_t stream) {
  const float* x    = (const float*)d_in[0];
  const float* mask = (const float*)d_in[1];
  const float* Wih[4] = {(const float*)d_in[2], (const float*)d_in[6],
                         (const float*)d_in[10], (const float*)d_in[14]};
  const float* Whh[4] = {(const float*)d_in[3], (const float*)d_in[7],
                         (const float*)d_in[11], (const float*)d_in[15]};
  const float* bih[4] = {(const float*)d_in[4], (const float*)d_in[8],
                         (const float*)d_in[12], (const float*)d_in[16]};
  const float* bhh[4] = {(const float*)d_in[5], (const float*)d_in[9],
                         (const float*)d_in[13], (const float*)d_in[17]};

  char* ws = (char*)d_ws;
  Bar*            bars  = (Bar*)ws;                              // 4 x 128B
  __hip_bfloat16* Xbf   = (__hip_bfloat16*)(ws + 4096);          // 32 MB
  __hip_bfloat16* Y0    = (__hip_bfloat16*)(ws + 33558528);      // 64 MB
  __hip_bfloat16* Y1    = (__hip_bfloat16*)(ws + 100667392);     // 64 MB
  __hip_bfloat16* WpIh0 = (__hip_bfloat16*)(ws + 167776256);     // 4 MB
  __hip_bfloat16* WpIh1 = (__hip_bfloat16*)(ws + 171970560);     // 8 MB
  __hip_bfloat16* WpHh  = (__hip_bfloat16*)(ws + 180359168);     // 8 MB
  float*          bsum  = (float*)(ws + 188747776);              // 32 KB
  __hip_bfloat16* Gbuf  = (__hip_bfloat16*)(ws + 188780544);     // 256 MB
  // total ws needed: 457,216,000 bytes

  float* out = (float*)d_out;
  float* hn = out + (size_t)S_LEN * BATCH * 1024;
  float* cn = hn + 2 * BATCH * 1024;

  hipMemsetAsync(bars, 0, 4 * sizeof(Bar), stream);

  // prep
  k_f32_to_bf16<<<8192, 256, 0, stream>>>(x, Xbf, SB * DDIM);
  for (int ld = 0; ld < 4; ld++) {
    int K = (ld < 2) ? 512 : 1024;
    __hip_bfloat16* dst = (ld < 2) ? (WpIh0 + (size_t)ld * 2048 * 512)
                                   : (WpIh1 + (size_t)(ld - 2) * 2048 * 1024);
    k_permW<<<(2048 * K) / 256, 256, 0, stream>>>(Wih[ld], dst, K);
    k_permW<<<(2048 * 512) / 256, 256, 0, stream>>>(Whh[ld], WpHh + (size_t)ld * 2048 * 512, 512);
    k_permB<<<8, 256, 0, stream>>>(bih[ld], bhh[ld], bsum + ld * 2048);
  }

  // layer 0
  k_gemm_in<<<dim3(256, 32), 256, 0, stream>>>(Xbf, WpIh0, bsum, Gbuf, 512);
  k_scan<<<64, 512, 0, stream>>>(Gbuf, WpHh, Y0, mask, nullptr, hn, cn, bars);
  // layer 1
  k_gemm_in<<<dim3(256, 32), 256, 0, stream>>>(Y0, WpIh1, bsum + 2 * 2048, Gbuf, 1024);
  k_scan<<<64, 512, 0, stream>>>(Gbuf, WpHh + (size_t)2 * 2048 * 512, Y1, mask,
                                 out, hn + 2 * BATCH * 512, cn + 2 * BATCH * 512,
                                 bars + 2);
}

// Round 3
// 5977.245 us; speedup vs baseline: 1.5328x; 1.3241x over previous
//
#include <hip/hip_runtime.h>
#include <hip/hip_bf16.h>
#include <stdint.h>

#define S_LEN 512
#define BATCH 64
#define DDIM  512
#define HID   512
#define SB    32768   // S_LEN*BATCH

typedef __attribute__((ext_vector_type(8))) short bf16x8;
typedef __attribute__((ext_vector_type(4))) short short4v;
typedef __attribute__((ext_vector_type(4))) float f32x4;

struct __align__(128) Bar { unsigned cnt; unsigned gen; };

__device__ __forceinline__ float bf2f(short s) {
  return __uint_as_float(((unsigned)(unsigned short)s) << 16);
}

__device__ __forceinline__ void gload_lds16(const void* g, void* l) {
  __builtin_amdgcn_global_load_lds(
      (const __attribute__((address_space(1))) void*)g,
      (__attribute__((address_space(3))) void*)l, 16, 0, 0);
}

// ---------- prep kernels ----------

__global__ void k_f32_to_bf16(const float* __restrict__ src,
                              __hip_bfloat16* __restrict__ dst, int n) {
  int i = (blockIdx.x * blockDim.x + threadIdx.x) * 8;
  if (i >= n) return;
  float4 a = *(const float4*)(src + i);
  float4 b = *(const float4*)(src + i + 4);
  __hip_bfloat16 t[8];
  t[0] = __float2bfloat16(a.x); t[1] = __float2bfloat16(a.y);
  t[2] = __float2bfloat16(a.z); t[3] = __float2bfloat16(a.w);
  t[4] = __float2bfloat16(b.x); t[5] = __float2bfloat16(b.y);
  t[6] = __float2bfloat16(b.z); t[7] = __float2bfloat16(b.w);
  *(bf16x8*)(dst + i) = *(bf16x8*)t;
}

__global__ void k_permW(const float* __restrict__ src,
                        __hip_bfloat16* __restrict__ dst, int K) {
  int idx = blockIdx.x * 256 + threadIdx.x;
  int p = idx / K, k = idx - p * K;
  int g = p & 3, j = p >> 2;
  dst[idx] = __float2bfloat16(src[(size_t)(g * HID + j) * K + k]);
}

__global__ void k_permB(const float* __restrict__ bih, const float* __restrict__ bhh,
                        float* __restrict__ dst) {
  int p = blockIdx.x * 256 + threadIdx.x;
  int g = p & 3, j = p >> 2;
  dst[p] = bih[g * HID + j] + bhh[g * HID + j];
}

// ---------- input-projection GEMM (unchanged, proven) ----------
__global__ __launch_bounds__(256) void k_gemm_in(
    const __hip_bfloat16* __restrict__ A,
    const __hip_bfloat16* __restrict__ W,
    const float* __restrict__ bsumL,
    __hip_bfloat16* __restrict__ G,
    int K) {
  __shared__ uint4 lds4[2048];
  char* ldsA = (char*)lds4;
  char* ldsB = (char*)lds4 + 16384;
  int tid = threadIdx.x, lane = tid & 63, wid = tid >> 6;
  int wm = wid >> 1, wn = wid & 1;
  int bm = blockIdx.x, by = blockIdx.y;
  int lr = lane & 15, lk = lane >> 4;
  f32x4 acc[4][4] = {};
  const char* gA = (const char*)A;
  const char* gW = (const char*)W;
  for (int kk = 0; kk < K; kk += 64) {
    #pragma unroll
    for (int i = 0; i < 4; i++) {
      int ch = i * 256 + tid;
      int row = ch >> 3, c16 = ch & 7;
      gload_lds16(gA + (size_t)(bm * 128 + row) * (K * 2) + kk * 2 + c16 * 16,
                  ldsA + (i * 256 + wid * 64) * 16);
      gload_lds16(gW + (size_t)(by * 128 + row) * (K * 2) + kk * 2 + c16 * 16,
                  ldsB + (i * 256 + wid * 64) * 16);
    }
    __syncthreads();
    #pragma unroll
    for (int ks = 0; ks < 2; ks++) {
      bf16x8 af[4], bfr[4];
      #pragma unroll
      for (int mi = 0; mi < 4; mi++) {
        int r = wm * 64 + mi * 16 + lr;
        af[mi] = *(const bf16x8*)(ldsA + r * 128 + ks * 64 + lk * 16);
      }
      #pragma unroll
      for (int ni = 0; ni < 4; ni++) {
        int r = wn * 64 + ni * 16 + lr;
        bfr[ni] = *(const bf16x8*)(ldsB + r * 128 + ks * 64 + lk * 16);
      }
      #pragma unroll
      for (int mi = 0; mi < 4; mi++)
        #pragma unroll
        for (int ni = 0; ni < 4; ni++)
          acc[mi][ni] = __builtin_amdgcn_mfma_f32_16x16x32_bf16(
              af[mi], bfr[ni], acc[mi][ni], 0, 0, 0);
    }
    __syncthreads();
  }
  #pragma unroll
  for (int ni = 0; ni < 4; ni++) {
    int n = by * 128 + wn * 64 + ni * 16 + lr;
    int d = n >> 11, p = n & 2047;
    float bias = bsumL[d * 2048 + p];
    #pragma unroll
    for (int mi = 0; mi < 4; mi++) {
      int mbase = bm * 128 + wm * 64 + mi * 16 + lk * 4;
      #pragma unroll
      for (int r = 0; r < 4; r++) {
        int m = mbase + r;
        G[((size_t)d * SB + m) * 2048 + p] =
            __float2bfloat16(acc[mi][ni][r] + bias);
      }
    }
  }
}

// ---------- persistent scan kernel ----------
// 64 blocks (bn 0..31 col-tiles, dir 0..1) x 512 threads. Whh fragments in
// regs; c-state in regs; h exchanged via relaxed agent-scope (sc1) atomics;
// hand-rolled monotone barrier, no cache-flushing fences; G prefetch depth 1.
__global__ __launch_bounds__(512, 1) void k_scan(
    const __hip_bfloat16* __restrict__ G,    // [2][SB][2048]
    const __hip_bfloat16* __restrict__ Whp,  // [2][2048][512] this layer
    __hip_bfloat16* __restrict__ Y,          // [SB][1024]
    const float* __restrict__ mask,          // [S][B]
    float* __restrict__ outH,                // f32 h out (layer1) or null
    float* __restrict__ hn, float* __restrict__ cn,
    Bar* __restrict__ bars) {                // [2] per-dir
  __shared__ char ldsH[65536];               // [64 rows][1024B], swizzled
  float* gatesF = (float*)ldsH;              // reuse: [64][68] f32
  int tid = threadIdx.x, lane = tid & 63, wid = tid >> 6;
  int bn = blockIdx.x & 31;
  int dir = blockIdx.x >> 5;
  int wm = wid >> 1, wn = wid & 1;
  int lr = lane & 15, lk = lane >> 4;
  int arow = wm * 16 + lr;
  Bar* bar = bars + dir;
  const __hip_bfloat16* Gd = G + (size_t)dir * SB * 2048;

  // cell-item mapping: pair p = tid; batch b = p>>3, unit-pair up = p&7
  int cb = tid >> 3, cup = tid & 7;

  // Whh B-fragments
  bf16x8 bfrag[16][2];
  {
    const __hip_bfloat16* w0 =
        Whp + (size_t)(dir * 2048 + bn * 64 + wn * 32 + lr) * 512;
    #pragma unroll
    for (int ni = 0; ni < 2; ni++)
      #pragma unroll
      for (int ks = 0; ks < 16; ks++)
        bfrag[ks][ni] = *(const bf16x8*)(w0 + (size_t)ni * 16 * 512 + ks * 32 + lk * 8);
  }

  float creg[2] = {0.f, 0.f};

  // prefetch G for step 0: one 16B load covers units 2*cup, 2*cup+1 (i,f,g,o x2)
  int t0 = dir ? (S_LEN - 1) : 0;
  bf16x8 gv = *(const bf16x8*)(Gd + ((size_t)t0 * 64 + cb) * 2048 + bn * 64 + cup * 8);

  for (int s = 0; s < S_LEN; ++s) {
    int t = dir ? (S_LEN - 1 - s) : s;
    f32x4 acc[2] = {};
    if (s > 0) {
      int tprev = dir ? t + 1 : t - 1;
      const char* srcH = (const char*)Y + (size_t)tprev * 131072 + dir * 1024;
      uint64_t tH[16];
      #pragma unroll
      for (int i = 0; i < 16; ++i) {
        int ch = i * 512 + tid, row = ch >> 7, c8 = ch & 127;
        tH[i] = __hip_atomic_load(
            (const uint64_t*)(srcH + (size_t)row * 2048 + c8 * 8),
            __ATOMIC_RELAXED, __HIP_MEMORY_SCOPE_AGENT);
      }
      #pragma unroll
      for (int i = 0; i < 16; ++i) {
        int ch = i * 512 + tid, row = ch >> 7, c8 = ch & 127;
        *(uint64_t*)(ldsH + row * 1024 + ((c8 * 8) ^ ((row & 7) << 4))) = tH[i];
      }
      __syncthreads();
      #pragma unroll
      for (int ks = 0; ks < 16; ++ks) {
        bf16x8 a = *(const bf16x8*)(
            ldsH + arow * 1024 + ((ks * 64 + lk * 16) ^ ((arow & 7) << 4)));
        acc[0] = __builtin_amdgcn_mfma_f32_16x16x32_bf16(a, bfrag[ks][0], acc[0], 0, 0, 0);
        acc[1] = __builtin_amdgcn_mfma_f32_16x16x32_bf16(a, bfrag[ks][1], acc[1], 0, 0, 0);
      }
      __syncthreads();
      #pragma unroll
      for (int ni = 0; ni < 2; ++ni)
        #pragma unroll
        for (int r = 0; r < 4; ++r)
          gatesF[(wm * 16 + lk * 4 + r) * 68 + wn * 32 + ni * 16 + lr] = acc[ni][r];
      __syncthreads();
    }

    // cell update: 2 adjacent units (b=cb, u=2*cup, 2*cup+1)
    float m = mask[t * 64 + cb];
    float h2v[2], c2v[2];
    #pragma unroll
    for (int it = 0; it < 2; ++it) {
      int u = cup * 2 + it;
      float gi = 0.f, gf = 0.f, gg = 0.f, go = 0.f;
      if (s > 0) {
        gi = gatesF[cb * 68 + u * 4 + 0];
        gf = gatesF[cb * 68 + u * 4 + 1];
        gg = gatesF[cb * 68 + u * 4 + 2];
        go = gatesF[cb * 68 + u * 4 + 3];
      }
      gi += bf2f(gv[it * 4 + 0]); gf += bf2f(gv[it * 4 + 1]);
      gg += bf2f(gv[it * 4 + 2]); go += bf2f(gv[it * 4 + 3]);
      float si = 1.f / (1.f + __expf(-gi));
      float sf = 1.f / (1.f + __expf(-gf));
      float so = 1.f / (1.f + __expf(-go));
      float tg = 1.f - 2.f / (1.f + __expf(2.f * gg));
      float c2 = sf * creg[it] + si * tg;
      float h2 = so * (1.f - 2.f / (1.f + __expf(2.f * c2)));
      h2 *= m; c2 *= m;
      creg[it] = c2; h2v[it] = h2; c2v[it] = c2;
    }
    // packed Y store (one 4B sc1 store): units 2*cup, 2*cup+1
    {
      __hip_bfloat16 b0 = __float2bfloat16(h2v[0]);
      __hip_bfloat16 b1 = __float2bfloat16(h2v[1]);
      unsigned w = (unsigned)*(unsigned short*)&b0 |
                   ((unsigned)*(unsigned short*)&b1 << 16);
      uint32_t* yw = (uint32_t*)((char*)Y + ((size_t)t * 64 + cb) * 2048 +
                                 dir * 1024 + (bn * 16 + cup * 2) * 2);
      __hip_atomic_store(yw, w, __ATOMIC_RELAXED, __HIP_MEMORY_SCOPE_AGENT);
    }
    if (outH) {
      float2* ow = (float2*)(outH + ((size_t)t * 64 + cb) * 1024 +
                             dir * 512 + bn * 16 + cup * 2);
      *ow = make_float2(h2v[0], h2v[1]);
    }
    if (s == S_LEN - 1) {
      size_t fi = (size_t)cb * 1024 + dir * 512 + bn * 16 + cup * 2;
      hn[fi] = h2v[0]; hn[fi + 1] = h2v[1];
      cn[fi] = c2v[0]; cn[fi + 1] = c2v[1];
    }

    if (s < S_LEN - 1) {
      // pin: Y store issued before the prefetch below
      asm volatile("" ::: "memory");
      int snx = s + 1;
      int tnx = dir ? (S_LEN - 1 - snx) : snx;
      bf16x8 gvn = *(const bf16x8*)(Gd + ((size_t)tnx * 64 + cb) * 2048 +
                                    bn * 64 + cup * 8);
      // drain Y store (and older), keep the 1 G prefetch in flight
      asm volatile("s_waitcnt vmcnt(1)" ::: "memory");
      __syncthreads();
      if (tid == 0) {
        unsigned prev = __hip_atomic_fetch_add(&bar->cnt, 1u, __ATOMIC_RELAXED,
                                               __HIP_MEMORY_SCOPE_AGENT);
        if ((prev & 31u) == 31u) {
          __hip_atomic_fetch_add(&bar->gen, 1u, __ATOMIC_RELAXED,
                                 __HIP_MEMORY_SCOPE_AGENT);
        } else {
          int guard = 0;
          while (__hip_atomic_load(&bar->gen, __ATOMIC_RELAXED,
                                   __HIP_MEMORY_SCOPE_AGENT) <= (unsigned)s) {
            __builtin_amdgcn_s_sleep(1);
            if (++guard > (1 << 24)) break;  // hang-proof bail
          }
        }
      }
      __syncthreads();
      gv = gvn;
    }
  }
}

// ---------- launcher ----------

extern "C" void kernel_launch(void* const* d_in, const int* in_sizes, int n_in,
                              void* d_out, int out_size, void* d_ws, size_t ws_size,
                              hipStream_t stream) {
  const float* x    = (const float*)d_in[0];
  const float* mask = (const float*)d_in[1];
  const float* Wih[4] = {(const float*)d_in[2], (const float*)d_in[6],
                         (const float*)d_in[10], (const float*)d_in[14]};
  const float* Whh[4] = {(const float*)d_in[3], (const float*)d_in[7],
                         (const float*)d_in[11], (const float*)d_in[15]};
  const float* bih[4] = {(const float*)d_in[4], (const float*)d_in[8],
                         (const float*)d_in[12], (const float*)d_in[16]};
  const float* bhh[4] = {(const float*)d_in[5], (const float*)d_in[9],
                         (const float*)d_in[13], (const float*)d_in[17]};

  char* ws = (char*)d_ws;
  Bar*            bars  = (Bar*)ws;                              // 4 x 128B
  __hip_bfloat16* Xbf   = (__hip_bfloat16*)(ws + 4096);          // 32 MB
  __hip_bfloat16* Y0    = (__hip_bfloat16*)(ws + 33558528);      // 64 MB
  __hip_bfloat16* Y1    = (__hip_bfloat16*)(ws + 100667392);     // 64 MB
  __hip_bfloat16* WpIh0 = (__hip_bfloat16*)(ws + 167776256);     // 4 MB
  __hip_bfloat16* WpIh1 = (__hip_bfloat16*)(ws + 171970560);     // 8 MB
  __hip_bfloat16* WpHh  = (__hip_bfloat16*)(ws + 180359168);     // 8 MB
  float*          bsum  = (float*)(ws + 188747776);              // 32 KB
  __hip_bfloat16* Gbuf  = (__hip_bfloat16*)(ws + 188780544);     // 256 MB
  // total ws needed: 457,216,000 bytes

  float* out = (float*)d_out;
  float* hn = out + (size_t)S_LEN * BATCH * 1024;
  float* cn = hn + 2 * BATCH * 1024;

  hipMemsetAsync(bars, 0, 4 * sizeof(Bar), stream);

  // prep
  k_f32_to_bf16<<<8192, 256, 0, stream>>>(x, Xbf, SB * DDIM);
  for (int ld = 0; ld < 4; ld++) {
    int K = (ld < 2) ? 512 : 1024;
    __hip_bfloat16* dst = (ld < 2) ? (WpIh0 + (size_t)ld * 2048 * 512)
                                   : (WpIh1 + (size_t)(ld - 2) * 2048 * 1024);
    k_permW<<<(2048 * K) / 256, 256, 0, stream>>>(Wih[ld], dst, K);
    k_permW<<<(2048 * 512) / 256, 256, 0, stream>>>(Whh[ld], WpHh + (size_t)ld * 2048 * 512, 512);
    k_permB<<<8, 256, 0, stream>>>(bih[ld], bhh[ld], bsum + ld * 2048);
  }

  // layer 0
  k_gemm_in<<<dim3(256, 32), 256, 0, stream>>>(Xbf, WpIh0, bsum, Gbuf, 512);
  k_scan<<<64, 512, 0, stream>>>(Gbuf, WpHh, Y0, mask, nullptr, hn, cn, bars);
  // layer 1
  k_gemm_in<<<dim3(256, 32), 256, 0, stream>>>(Y0, WpIh1, bsum + 2 * 2048, Gbuf, 1024);
  k_scan<<<64, 512, 0, stream>>>(Gbuf, WpHh + (size_t)2 * 2048 * 512, Y1, mask,
                                 out, hn + 2 * BATCH * 512, cn + 2 * BATCH * 512,
                                 bars + 2);
}

// Round 4
// 4869.374 us; speedup vs baseline: 1.8815x; 1.2275x over previous
//
#include <hip/hip_runtime.h>
#include <hip/hip_bf16.h>
#include <stdint.h>

#define S_LEN 512
#define BATCH 64
#define DDIM  512
#define HID   512
#define SB    32768   // S_LEN*BATCH

typedef __attribute__((ext_vector_type(8))) short bf16x8;
typedef __attribute__((ext_vector_type(4))) float f32x4;

__device__ __forceinline__ float bf2f(short s) {
  return __uint_as_float(((unsigned)(unsigned short)s) << 16);
}

__device__ __forceinline__ void gload_lds16(const void* g, void* l) {
  __builtin_amdgcn_global_load_lds(
      (const __attribute__((address_space(1))) void*)g,
      (__attribute__((address_space(3))) void*)l, 16, 0, 0);
}

// ---------- prep kernels ----------

__global__ void k_f32_to_bf16(const float* __restrict__ src,
                              __hip_bfloat16* __restrict__ dst, int n) {
  int i = (blockIdx.x * blockDim.x + threadIdx.x) * 8;
  if (i >= n) return;
  float4 a = *(const float4*)(src + i);
  float4 b = *(const float4*)(src + i + 4);
  __hip_bfloat16 t[8];
  t[0] = __float2bfloat16(a.x); t[1] = __float2bfloat16(a.y);
  t[2] = __float2bfloat16(a.z); t[3] = __float2bfloat16(a.w);
  t[4] = __float2bfloat16(b.x); t[5] = __float2bfloat16(b.y);
  t[6] = __float2bfloat16(b.z); t[7] = __float2bfloat16(b.w);
  *(bf16x8*)(dst + i) = *(bf16x8*)t;
}

__global__ void k_permW(const float* __restrict__ src,
                        __hip_bfloat16* __restrict__ dst, int K) {
  int idx = blockIdx.x * 256 + threadIdx.x;
  int p = idx / K, k = idx - p * K;
  int g = p & 3, j = p >> 2;
  dst[idx] = __float2bfloat16(src[(size_t)(g * HID + j) * K + k]);
}

__global__ void k_permB(const float* __restrict__ bih, const float* __restrict__ bhh,
                        float* __restrict__ dst) {
  int p = blockIdx.x * 256 + threadIdx.x;
  int g = p & 3, j = p >> 2;
  dst[p] = bih[g * HID + j] + bhh[g * HID + j];
}

// ---------- input-projection GEMM (unchanged, proven) ----------
__global__ __launch_bounds__(256) void k_gemm_in(
    const __hip_bfloat16* __restrict__ A,
    const __hip_bfloat16* __restrict__ W,
    const float* __restrict__ bsumL,
    __hip_bfloat16* __restrict__ G,
    int K) {
  __shared__ uint4 lds4[2048];
  char* ldsA = (char*)lds4;
  char* ldsB = (char*)lds4 + 16384;
  int tid = threadIdx.x, lane = tid & 63, wid = tid >> 6;
  int wm = wid >> 1, wn = wid & 1;
  int bm = blockIdx.x, by = blockIdx.y;
  int lr = lane & 15, lk = lane >> 4;
  f32x4 acc[4][4] = {};
  const char* gA = (const char*)A;
  const char* gW = (const char*)W;
  for (int kk = 0; kk < K; kk += 64) {
    #pragma unroll
    for (int i = 0; i < 4; i++) {
      int ch = i * 256 + tid;
      int row = ch >> 3, c16 = ch & 7;
      gload_lds16(gA + (size_t)(bm * 128 + row) * (K * 2) + kk * 2 + c16 * 16,
                  ldsA + (i * 256 + wid * 64) * 16);
      gload_lds16(gW + (size_t)(by * 128 + row) * (K * 2) + kk * 2 + c16 * 16,
                  ldsB + (i * 256 + wid * 64) * 16);
    }
    __syncthreads();
    #pragma unroll
    for (int ks = 0; ks < 2; ks++) {
      bf16x8 af[4], bfr[4];
      #pragma unroll
      for (int mi = 0; mi < 4; mi++) {
        int r = wm * 64 + mi * 16 + lr;
        af[mi] = *(const bf16x8*)(ldsA + r * 128 + ks * 64 + lk * 16);
      }
      #pragma unroll
      for (int ni = 0; ni < 4; ni++) {
        int r = wn * 64 + ni * 16 + lr;
        bfr[ni] = *(const bf16x8*)(ldsB + r * 128 + ks * 64 + lk * 16);
      }
      #pragma unroll
      for (int mi = 0; mi < 4; mi++)
        #pragma unroll
        for (int ni = 0; ni < 4; ni++)
          acc[mi][ni] = __builtin_amdgcn_mfma_f32_16x16x32_bf16(
              af[mi], bfr[ni], acc[mi][ni], 0, 0, 0);
    }
    __syncthreads();
  }
  #pragma unroll
  for (int ni = 0; ni < 4; ni++) {
    int n = by * 128 + wn * 64 + ni * 16 + lr;
    int d = n >> 11, p = n & 2047;
    float bias = bsumL[d * 2048 + p];
    #pragma unroll
    for (int mi = 0; mi < 4; mi++) {
      int mbase = bm * 128 + wm * 64 + mi * 16 + lk * 4;
      #pragma unroll
      for (int r = 0; r < 4; r++) {
        int m = mbase + r;
        G[((size_t)d * SB + m) * 2048 + p] =
            __float2bfloat16(acc[mi][ni][r] + bias);
      }
    }
  }
}

// ---------- persistent scan kernel, sentinel-poll sync ----------
// 64 blocks (bn 0..31 col-tiles, dir 0..1) x 512 threads. No barrier: Y is
// step-indexed + pre-filled with bf16 sentinel 0xFFFF; consumers spin on
// their own sc1 data loads. One IC hop per step instead of three.
__global__ __launch_bounds__(512, 1) void k_scan(
    const __hip_bfloat16* __restrict__ G,    // [2][SB][2048]
    const __hip_bfloat16* __restrict__ Whp,  // [2][2048][512] this layer
    __hip_bfloat16* __restrict__ Y,          // [SB][1024], sentinel-filled
    const float* __restrict__ mask,          // [S][B]
    float* __restrict__ outH,                // f32 h out (layer1) or null
    float* __restrict__ hn, float* __restrict__ cn) {
  __shared__ char ldsH[65536];               // [64 rows][1024B], swizzled
  __shared__ float gatesF[64 * 68];          // separate region (no alias)
  int tid = threadIdx.x, lane = tid & 63, wid = tid >> 6;
  int bn = blockIdx.x & 31;
  int dir = blockIdx.x >> 5;
  int wm = wid >> 1, wn = wid & 1;
  int lr = lane & 15, lk = lane >> 4;
  int arow = wm * 16 + lr;
  const __hip_bfloat16* Gd = G + (size_t)dir * SB * 2048;

  // cell-item mapping: batch cb = tid>>3, unit-pair cup = tid&7
  int cb = tid >> 3, cup = tid & 7;

  // Whh B-fragments (held in registers for the whole scan)
  bf16x8 bfrag[16][2];
  {
    const __hip_bfloat16* w0 =
        Whp + (size_t)(dir * 2048 + bn * 64 + wn * 32 + lr) * 512;
    #pragma unroll
    for (int ni = 0; ni < 2; ni++)
      #pragma unroll
      for (int ks = 0; ks < 16; ks++)
        bfrag[ks][ni] = *(const bf16x8*)(w0 + (size_t)ni * 16 * 512 + ks * 32 + lk * 8);
  }

  float creg[2] = {0.f, 0.f};

  // prefetch G + mask for step 0
  int t0 = dir ? (S_LEN - 1) : 0;
  bf16x8 gv = *(const bf16x8*)(Gd + ((size_t)t0 * 64 + cb) * 2048 + bn * 64 + cup * 8);
  float mreg = mask[t0 * 64 + cb];

  for (int s = 0; s < S_LEN; ++s) {
    int t = dir ? (S_LEN - 1 - s) : s;
    f32x4 acc[2] = {};
    if (s > 0) {
      int tprev = dir ? t + 1 : t - 1;
      const char* srcH = (const char*)Y + (size_t)tprev * 131072 + dir * 1024;
      uint64_t tH[16];
      // sentinel-poll: 16 independent 8B sc1 loads, retry until no half
      // is 0xFFFF (bf16 NaN, unreachable for |h|<=1)
      int guard = 0;
      for (;;) {
        #pragma unroll
        for (int i = 0; i < 16; ++i) {
          int ch = i * 512 + tid, row = ch >> 7, c8 = ch & 127;
          tH[i] = __hip_atomic_load(
              (const uint64_t*)(srcH + (size_t)row * 2048 + c8 * 8),
              __ATOMIC_RELAXED, __HIP_MEMORY_SCOPE_AGENT);
        }
        unsigned long long bad = 0;
        #pragma unroll
        for (int i = 0; i < 16; ++i) {
          uint64_t v = tH[i];
          bad |= ((v & 0xFFFFull) == 0xFFFFull);
          bad |= (((v >> 32) & 0xFFFFull) == 0xFFFFull);
        }
        if (!bad) break;
        __builtin_amdgcn_s_sleep(1);
        if (++guard > (1 << 14)) break;  // hang-proof bail
      }
      #pragma unroll
      for (int i = 0; i < 16; ++i) {
        int ch = i * 512 + tid, row = ch >> 7, c8 = ch & 127;
        *(uint64_t*)(ldsH + row * 1024 + ((c8 * 8) ^ ((row & 7) << 4))) = tH[i];
      }
      __syncthreads();
      #pragma unroll
      for (int ks = 0; ks < 16; ++ks) {
        bf16x8 a = *(const bf16x8*)(
            ldsH + arow * 1024 + ((ks * 64 + lk * 16) ^ ((arow & 7) << 4)));
        acc[0] = __builtin_amdgcn_mfma_f32_16x16x32_bf16(a, bfrag[ks][0], acc[0], 0, 0, 0);
        acc[1] = __builtin_amdgcn_mfma_f32_16x16x32_bf16(a, bfrag[ks][1], acc[1], 0, 0, 0);
      }
      #pragma unroll
      for (int ni = 0; ni < 2; ++ni)
        #pragma unroll
        for (int r = 0; r < 4; ++r)
          gatesF[(wm * 16 + lk * 4 + r) * 68 + wn * 32 + ni * 16 + lr] = acc[ni][r];
      __syncthreads();
    }

    // cell update: 2 adjacent units (b=cb, u=2*cup, 2*cup+1)
    float h2v[2], c2v[2];
    #pragma unroll
    for (int it = 0; it < 2; ++it) {
      int u = cup * 2 + it;
      float gi = 0.f, gf = 0.f, gg = 0.f, go = 0.f;
      if (s > 0) {
        gi = gatesF[cb * 68 + u * 4 + 0];
        gf = gatesF[cb * 68 + u * 4 + 1];
        gg = gatesF[cb * 68 + u * 4 + 2];
        go = gatesF[cb * 68 + u * 4 + 3];
      }
      gi += bf2f(gv[it * 4 + 0]); gf += bf2f(gv[it * 4 + 1]);
      gg += bf2f(gv[it * 4 + 2]); go += bf2f(gv[it * 4 + 3]);
      float si = 1.f / (1.f + __expf(-gi));
      float sf = 1.f / (1.f + __expf(-gf));
      float so = 1.f / (1.f + __expf(-go));
      float tg = 1.f - 2.f / (1.f + __expf(2.f * gg));
      float c2 = sf * creg[it] + si * tg;
      float h2 = so * (1.f - 2.f / (1.f + __expf(2.f * c2)));
      h2 *= mreg; c2 *= mreg;
      creg[it] = c2; h2v[it] = h2; c2v[it] = c2;
    }
    // packed Y publish (one 4B sc1 store; the data IS the ready flag)
    {
      __hip_bfloat16 b0 = __float2bfloat16(h2v[0]);
      __hip_bfloat16 b1 = __float2bfloat16(h2v[1]);
      unsigned w = (unsigned)*(unsigned short*)&b0 |
                   ((unsigned)*(unsigned short*)&b1 << 16);
      uint32_t* yw = (uint32_t*)((char*)Y + ((size_t)t * 64 + cb) * 2048 +
                                 dir * 1024 + (bn * 16 + cup * 2) * 2);
      __hip_atomic_store(yw, w, __ATOMIC_RELAXED, __HIP_MEMORY_SCOPE_AGENT);
    }
    if (outH) {
      float2* ow = (float2*)(outH + ((size_t)t * 64 + cb) * 1024 +
                             dir * 512 + bn * 16 + cup * 2);
      *ow = make_float2(h2v[0], h2v[1]);
    }
    if (s == S_LEN - 1) {
      size_t fi = (size_t)cb * 1024 + dir * 512 + bn * 16 + cup * 2;
      hn[fi] = h2v[0]; hn[fi + 1] = h2v[1];
      cn[fi] = c2v[0]; cn[fi + 1] = c2v[1];
    }

    if (s < S_LEN - 1) {
      // pin program order: Y store issues before next-step prefetch/polls
      asm volatile("" ::: "memory");
      int tnx = dir ? (t - 1) : (t + 1);
      gv = *(const bf16x8*)(Gd + ((size_t)tnx * 64 + cb) * 2048 + bn * 64 + cup * 8);
      mreg = mask[tnx * 64 + cb];
    }
  }
}

// ---------- launcher ----------

extern "C" void kernel_launch(void* const* d_in, const int* in_sizes, int n_in,
                              void* d_out, int out_size, void* d_ws, size_t ws_size,
                              hipStream_t stream) {
  const float* x    = (const float*)d_in[0];
  const float* mask = (const float*)d_in[1];
  const float* Wih[4] = {(const float*)d_in[2], (const float*)d_in[6],
                         (const float*)d_in[10], (const float*)d_in[14]};
  const float* Whh[4] = {(const float*)d_in[3], (const float*)d_in[7],
                         (const float*)d_in[11], (const float*)d_in[15]};
  const float* bih[4] = {(const float*)d_in[4], (const float*)d_in[8],
                         (const float*)d_in[12], (const float*)d_in[16]};
  const float* bhh[4] = {(const float*)d_in[5], (const float*)d_in[9],
                         (const float*)d_in[13], (const float*)d_in[17]};

  char* ws = (char*)d_ws;
  __hip_bfloat16* Xbf   = (__hip_bfloat16*)(ws);                 // 32 MB
  __hip_bfloat16* Y0    = (__hip_bfloat16*)(ws + 33554432);      // 64 MB
  __hip_bfloat16* Y1    = (__hip_bfloat16*)(ws + 100663296);     // 64 MB
  __hip_bfloat16* WpIh0 = (__hip_bfloat16*)(ws + 167772160);     // 4 MB
  __hip_bfloat16* WpIh1 = (__hip_bfloat16*)(ws + 171966464);     // 8 MB
  __hip_bfloat16* WpHh  = (__hip_bfloat16*)(ws + 180355072);     // 8 MB
  float*          bsum  = (float*)(ws + 188743680);              // 32 KB
  __hip_bfloat16* Gbuf  = (__hip_bfloat16*)(ws + 188776448);     // 256 MB
  // total ws needed: ~457 MB

  float* out = (float*)d_out;
  float* hn = out + (size_t)S_LEN * BATCH * 1024;
  float* cn = hn + 2 * BATCH * 1024;

  // sentinel-fill the h-exchange buffers (0xFFFF bf16 = NaN, unreachable)
  hipMemsetAsync(Y0, 0xFF, (size_t)SB * 1024 * 2, stream);
  hipMemsetAsync(Y1, 0xFF, (size_t)SB * 1024 * 2, stream);

  // prep
  k_f32_to_bf16<<<8192, 256, 0, stream>>>(x, Xbf, SB * DDIM);
  for (int ld = 0; ld < 4; ld++) {
    int K = (ld < 2) ? 512 : 1024;
    __hip_bfloat16* dst = (ld < 2) ? (WpIh0 + (size_t)ld * 2048 * 512)
                                   : (WpIh1 + (size_t)(ld - 2) * 2048 * 1024);
    k_permW<<<(2048 * K) / 256, 256, 0, stream>>>(Wih[ld], dst, K);
    k_permW<<<(2048 * 512) / 256, 256, 0, stream>>>(Whh[ld], WpHh + (size_t)ld * 2048 * 512, 512);
    k_permB<<<8, 256, 0, stream>>>(bih[ld], bhh[ld], bsum + ld * 2048);
  }

  // layer 0
  k_gemm_in<<<dim3(256, 32), 256, 0, stream>>>(Xbf, WpIh0, bsum, Gbuf, 512);
  k_scan<<<64, 512, 0, stream>>>(Gbuf, WpHh, Y0, mask, nullptr, hn, cn);
  // layer 1
  k_gemm_in<<<dim3(256, 32), 256, 0, stream>>>(Y0, WpIh1, bsum + 2 * 2048, Gbuf, 1024);
  k_scan<<<64, 512, 0, stream>>>(Gbuf, WpHh + (size_t)2 * 2048 * 512, Y1, mask,
                                 out, hn + 2 * BATCH * 512, cn + 2 * BATCH * 512);
}